// Round 8
// baseline (551.585 us; speedup 1.0000x reference)
//
#include <hip/hip_runtime.h>
#include <hip/hip_bf16.h>

#define NEG_SLOPE 0.01f

typedef long long i64;
typedef __hip_bfloat16 bf16;

__device__ __forceinline__ float lrelu(float x) { return x > 0.f ? x : NEG_SLOPE * x; }
__device__ __forceinline__ float b2f(bf16 v) { return __bfloat162float(v); }
__device__ __forceinline__ float lo2f(unsigned u) { return __uint_as_float(u << 16); }
__device__ __forceinline__ float hi2f(unsigned u) { return __uint_as_float(u & 0xffff0000u); }
__device__ __forceinline__ unsigned pk2(float a, float b) {
    unsigned ua = __bfloat16_as_ushort(__float2bfloat16(a));
    unsigned ub = __bfloat16_as_ushort(__float2bfloat16(b));
    return ua | (ub << 16);
}
__device__ __forceinline__ void acc8(float* h, uint4 u) {
    h[0] += lo2f(u.x); h[1] += hi2f(u.x);
    h[2] += lo2f(u.y); h[3] += hi2f(u.y);
    h[4] += lo2f(u.z); h[5] += hi2f(u.z);
    h[6] += lo2f(u.w); h[7] += hi2f(u.w);
}

// XCD-aware decode: pin batch b to XCD (wgid&7) so each XCD's gather slice is
// L2-resident. Bijective for CBc%8==0; plain decode otherwise.
__device__ __forceinline__ void decode_bxb(int wg, int NB, int CBc, int& b, int& xb) {
    if ((CBc & 7) == 0) {
        int xcd = wg & 7, k = wg >> 3;
        int bl = k / NB;
        xb = k - bl * NB;
        b = xcd + 8 * bl;
    } else {
        b = wg / NB;
        xb = wg - b * NB;
    }
}

// ================= degree (batch-independent) =================
__global__ __launch_bounds__(256) void k_deg(const int* __restrict__ edges,
                                             int* __restrict__ indeg, int E) {
    int e = blockIdx.x * 256 + threadIdx.x;
    if (e < E) atomicAdd(&indeg[edges[2 * e + 1]], 1);
}

// ============== degree histogram (64 bins, LDS pre-aggregated) ==============
__global__ __launch_bounds__(256) void k_hist(const int* __restrict__ indeg,
                                              int* __restrict__ hist, int V) {
    __shared__ int lh[64];
    if (threadIdx.x < 64) lh[threadIdx.x] = 0;
    __syncthreads();
    int v = blockIdx.x * 256 + threadIdx.x;
    if (v < V) atomicAdd(&lh[min(indeg[v], 63)], 1);
    __syncthreads();
    if (threadIdx.x < 64 && lh[threadIdx.x]) atomicAdd(&hist[threadIdx.x], lh[threadIdx.x]);
}

__global__ __launch_bounds__(64) void k_hscan(const int* __restrict__ hist,
                                              int* __restrict__ hbase,
                                              int* __restrict__ hcnt) {
    __shared__ int s[64];
    int t = threadIdx.x;
    int x = hist[t];
    s[t] = x;
    __syncthreads();
    for (int off = 1; off < 64; off <<= 1) {
        int u = (t >= off) ? s[t - off] : 0;
        __syncthreads();
        s[t] += u;
        __syncthreads();
    }
    hbase[t] = s[t] - x;   // exclusive
    hcnt[t] = 0;
}

// place: slot = degree-sorted position; emit perm maps + permuted deg/dinv
__global__ __launch_bounds__(256) void k_place(const int* __restrict__ indeg,
                                               const int* __restrict__ hbase,
                                               int* __restrict__ hcnt,
                                               int* __restrict__ slotOf,
                                               int* __restrict__ sperm,
                                               int* __restrict__ deg_p,
                                               float* __restrict__ dinv_o,
                                               float* __restrict__ dinv_p, int V) {
    __shared__ int lh[64], lb[64];
    if (threadIdx.x < 64) lh[threadIdx.x] = 0;
    __syncthreads();
    int v = blockIdx.x * 256 + threadIdx.x;
    int d = 0, r = 0;
    bool ok = v < V;
    if (ok) { d = min(indeg[v], 63); r = atomicAdd(&lh[d], 1); }
    __syncthreads();
    if (threadIdx.x < 64)
        lb[threadIdx.x] = lh[threadIdx.x] ? atomicAdd(&hcnt[threadIdx.x], lh[threadIdx.x]) : 0;
    __syncthreads();
    if (ok) {
        int slot = hbase[d] + lb[d] + r;
        slotOf[v] = slot;
        sperm[slot] = v;
        deg_p[slot] = indeg[v];
        float di = rsqrtf((float)indeg[v] + 1.0f);
        dinv_o[v] = di;
        dinv_p[slot] = di;
    }
}

// identity permutation (generic-H fallback path)
__global__ __launch_bounds__(256) void k_ident(const int* __restrict__ indeg,
                                               int* __restrict__ slotOf,
                                               int* __restrict__ sperm,
                                               int* __restrict__ deg_p,
                                               float* __restrict__ dinv_o,
                                               float* __restrict__ dinv_p, int V) {
    int v = blockIdx.x * 256 + threadIdx.x;
    if (v >= V) return;
    slotOf[v] = v; sperm[v] = v; deg_p[v] = indeg[v];
    float di = rsqrtf((float)indeg[v] + 1.0f);
    dinv_o[v] = di; dinv_p[v] = di;
}

// ================= CSR build over permuted slots =================
__global__ __launch_bounds__(256) void k_scan1(const int* __restrict__ degp,
                                               int* __restrict__ rowptr,
                                               int* __restrict__ bsum, int V) {
    __shared__ int s[256];
    int i = blockIdx.x * 256 + threadIdx.x;
    int x = (i < V) ? degp[i] : 0;
    s[threadIdx.x] = x;
    __syncthreads();
    for (int off = 1; off < 256; off <<= 1) {
        int t = (threadIdx.x >= (unsigned)off) ? s[threadIdx.x - off] : 0;
        __syncthreads();
        s[threadIdx.x] += t;
        __syncthreads();
    }
    if (i < V) rowptr[i] = s[threadIdx.x] - x;  // exclusive within block
    if (threadIdx.x == 255) bsum[blockIdx.x] = s[255];
}

__global__ __launch_bounds__(1024) void k_scan2(int* __restrict__ bsum, int NB) {
    __shared__ int s[1024];
    __shared__ int srun;
    if (threadIdx.x == 0) srun = 0;
    __syncthreads();
    for (int base = 0; base < NB; base += 1024) {
        int i = base + threadIdx.x;
        int x = (i < NB) ? bsum[i] : 0;
        s[threadIdx.x] = x;
        __syncthreads();
        for (int off = 1; off < 1024; off <<= 1) {
            int t = (threadIdx.x >= (unsigned)off) ? s[threadIdx.x - off] : 0;
            __syncthreads();
            s[threadIdx.x] += t;
            __syncthreads();
        }
        int run = srun;
        if (i < NB) bsum[i] = run + s[threadIdx.x] - x;  // exclusive
        __syncthreads();
        if (threadIdx.x == 1023) srun = run + s[1023];
        __syncthreads();
    }
}

__global__ __launch_bounds__(256) void k_scan3(int* __restrict__ rowptr,
                                               const int* __restrict__ bsum,
                                               int V, int E) {
    int i = blockIdx.x * 256 + threadIdx.x;
    if (i < V) rowptr[i] += bsum[blockIdx.x];
    if (i == 0) rowptr[V] = E;
}

__global__ __launch_bounds__(256) void k_rp2(const int* __restrict__ rowptr,
                                             int2* __restrict__ rp2, int V) {
    int v = blockIdx.x * 256 + threadIdx.x;
    if (v < V) rp2[v] = make_int2(rowptr[v], rowptr[v + 1]);
}

// fill: col_o = orig src id (for verts gathers), col_p = permuted src slot;
// ep = edge endpoints in slot space (for k_mid).
__global__ __launch_bounds__(256) void k_fill2(const int* __restrict__ edges,
                                               const int* __restrict__ rowptr,
                                               const int* __restrict__ slotOf,
                                               int* __restrict__ cur,
                                               int* __restrict__ col_o,
                                               int* __restrict__ col_p,
                                               int2* __restrict__ ep, int E) {
    int e = blockIdx.x * 256 + threadIdx.x;
    if (e >= E) return;
    int s = edges[2 * e], d = edges[2 * e + 1];
    int ss = slotOf[s], ds = slotOf[d];
    ep[e] = make_int2(ss, ds);
    int p = atomicAdd(&cur[ds], 1);
    int idx = rowptr[ds] + p;
    col_o[idx] = s;
    col_p[idx] = ss;
}

// ========== H==16: fused layer1+layer2 (linearity trick, slot space) ==========
__global__ __launch_bounds__(256) void k_gl12(const int2* __restrict__ rp2,
                                              const int* __restrict__ col_o,
                                              const int* __restrict__ sperm,
                                              const float* __restrict__ verts,
                                              const float* __restrict__ W1,
                                              const float* __restrict__ b1,
                                              const float* __restrict__ W2,
                                              const float* __restrict__ dinv_o,
                                              const float* __restrict__ dinv_p,
                                              bf16* __restrict__ PB,
                                              float* __restrict__ Q,
                                              int b0, int V, int NB, int CBc) {
    int b, xb;
    decode_bxb(blockIdx.x, NB, CBc, b, xb);
    int v = xb * 256 + threadIdx.x;   // slot
    if (v >= V) return;
    i64 vg = (i64)(b0 + b) * V;   // global verts base
    i64 vb = (i64)b * V;          // workspace base
    float di = dinv_p[v];
    const float* xv = verts + (vg + sperm[v]) * 3;
    float c0 = di * xv[0], c1 = di * xv[1], c2 = di * xv[2];
    int2 r = rp2[v];
    int j = r.x;
    for (; j + 1 < r.y; j += 2) {
        int s0 = col_o[j], s1 = col_o[j + 1];
        float d0 = dinv_o[s0], d1 = dinv_o[s1];
        const float* p0 = verts + (vg + s0) * 3;
        const float* p1 = verts + (vg + s1) * 3;
        c0 += d0 * p0[0] + d1 * p1[0];
        c1 += d0 * p0[1] + d1 * p1[1];
        c2 += d0 * p0[2] + d1 * p1[2];
    }
    if (j < r.y) {
        int s0 = col_o[j];
        float d0 = dinv_o[s0];
        const float* p0 = verts + (vg + s0) * 3;
        c0 += d0 * p0[0]; c1 += d0 * p0[1]; c2 += d0 * p0[2];
    }
    float h[16];
#pragma unroll
    for (int f = 0; f < 16; ++f)
        h[f] = lrelu(di * (c0 * W1[f] + c1 * W1[16 + f] + c2 * W1[32 + f]) + b1[f]);
    float g[16];
#pragma unroll
    for (int f = 0; f < 16; ++f) g[f] = 0.f;
#pragma unroll
    for (int k = 0; k < 16; ++k) {
        float hk = h[k];
#pragma unroll
        for (int f = 0; f < 16; ++f) g[f] += hk * W2[k * 16 + f];
    }
#pragma unroll
    for (int f = 0; f < 16; ++f) g[f] *= di;
    i64 m = vb + v;
    uint4* Pp = (uint4*)(PB + m * 16);
    Pp[0] = make_uint4(pk2(g[0], g[1]), pk2(g[2], g[3]), pk2(g[4], g[5]), pk2(g[6], g[7]));
    Pp[1] = make_uint4(pk2(g[8], g[9]), pk2(g[10], g[11]), pk2(g[12], g[13]), pk2(g[14], g[15]));
    float4* Qp = (float4*)(Q + m * 16);
#pragma unroll
    for (int q = 0; q < 4; ++q)
        Qp[q] = make_float4(g[4 * q], g[4 * q + 1], g[4 * q + 2], g[4 * q + 3]);
}

// ========== H==16: fused gather + layer3 (16 -> 3), slot space ==========
__global__ __launch_bounds__(256) void k_gl3(const int2* __restrict__ rp2,
                                             const int* __restrict__ col_p,
                                             const float* __restrict__ W3,
                                             const float* __restrict__ b2,
                                             const float* __restrict__ dinv_p,
                                             const bf16* __restrict__ Pin,
                                             const float* __restrict__ Q,
                                             float* __restrict__ R,
                                             int V, int NB, int CBc) {
    int b, xb;
    decode_bxb(blockIdx.x, NB, CBc, b, xb);
    int v = xb * 256 + threadIdx.x;
    if (v >= V) return;
    i64 vb = (i64)b * V;
    i64 m = vb + v;
    float h[16];
    const float4* Qin = (const float4*)(Q + m * 16);
#pragma unroll
    for (int q = 0; q < 4; ++q) {
        float4 t = Qin[q];
        h[4 * q] = t.x; h[4 * q + 1] = t.y; h[4 * q + 2] = t.z; h[4 * q + 3] = t.w;
    }
    const uint4* Pb = (const uint4*)(Pin + vb * 16);
    int2 r = rp2[v];
    int j = r.x;
    for (; j + 1 < r.y; j += 2) {
        size_t u0 = (size_t)col_p[j] * 2, u1 = (size_t)col_p[j + 1] * 2;
        uint4 q0 = Pb[u0], q1 = Pb[u0 + 1];
        uint4 c0 = Pb[u1], c1 = Pb[u1 + 1];
        acc8(h, q0); acc8(h + 8, q1);
        acc8(h, c0); acc8(h + 8, c1);
    }
    if (j < r.y) {
        size_t u0 = (size_t)col_p[j] * 2;
        uint4 q0 = Pb[u0], q1 = Pb[u0 + 1];
        acc8(h, q0); acc8(h + 8, q1);
    }
    float di = dinv_p[v];
    float g0 = 0.f, g1 = 0.f, g2 = 0.f;
#pragma unroll
    for (int k = 0; k < 16; ++k) {
        float hk = lrelu(di * h[k] + b2[k]);
        g0 += hk * W3[k * 3 + 0];
        g1 += hk * W3[k * 3 + 1];
        g2 += hk * W3[k * 3 + 2];
    }
    ((float4*)R)[m] = make_float4(di * g0, di * g1, di * g2, 0.f);
}

// fused gather + final vertex update (slot space; out0 scattered by sperm)
__global__ __launch_bounds__(256) void k_gvert(const int2* __restrict__ rp2,
                                               const int* __restrict__ col_p,
                                               const int* __restrict__ sperm,
                                               const float* __restrict__ x,
                                               const float* __restrict__ b3,
                                               const float* __restrict__ dinv_p,
                                               const float* __restrict__ R,
                                               float* __restrict__ Vpos,
                                               float* __restrict__ out0,
                                               int b0, int V, int E, int NB, int CBc) {
    int b, xb;
    decode_bxb(blockIdx.x, NB, CBc, b, xb);
    int v = xb * 256 + threadIdx.x;
    if (v >= V) return;
    i64 vb = (i64)b * V;
    i64 m = vb + v;
    const float4* Rb = (const float4*)R + vb;
    float4 s = Rb[v];
    int2 r = rp2[v];
    int j = r.x;
    for (; j + 1 < r.y; j += 2) {
        float4 t0 = Rb[col_p[j]];
        float4 t1 = Rb[col_p[j + 1]];
        s.x += t0.x + t1.x; s.y += t0.y + t1.y; s.z += t0.z + t1.z;
    }
    if (j < r.y) {
        float4 t0 = Rb[col_p[j]];
        s.x += t0.x; s.y += t0.y; s.z += t0.z;
    }
    float di = dinv_p[v];
    int bg = b0 + b;
    int vo = sperm[v];
    i64 n = (i64)bg * V + vo;
    float p0 = x[n * 3]     + di * s.x + b3[0];
    float p1 = x[n * 3 + 1] + di * s.y + b3[1];
    float p2 = x[n * 3 + 2] + di * s.z + b3[2];
    ((float4*)Vpos)[m] = make_float4(p0, p1, p2, 0.f);
    i64 o = ((i64)bg * (V + E) + vo) * 3;   // scattered 12B; L2 absorbs
    out0[o]     = p0;
    out0[o + 1] = p1;
    out0[o + 2] = p2;
}

__global__ __launch_bounds__(256) void k_mid(const int2* __restrict__ ep,
                                             const float* __restrict__ Vpos,
                                             float* __restrict__ out0,
                                             int b0, int V, int E, int NB, int CBc) {
    int b, xe;
    decode_bxb(blockIdx.x, NB, CBc, b, xe);
    int e = xe * 256 + threadIdx.x;
    if (e >= E) return;
    int2 sd = ep[e];
    float4 ps = ((const float4*)Vpos)[(i64)b * V + sd.x];
    float4 pd = ((const float4*)Vpos)[(i64)b * V + sd.y];
    i64 o = ((i64)(b0 + b) * (V + E) + V + e) * 3;
    __builtin_nontemporal_store(0.5f * (ps.x + pd.x), out0 + o);
    __builtin_nontemporal_store(0.5f * (ps.y + pd.y), out0 + o + 1);
    __builtin_nontemporal_store(0.5f * (ps.z + pd.z), out0 + o + 2);
}

__global__ __launch_bounds__(256) void k_faces(const int* __restrict__ faces,
                                               float* __restrict__ out1,
                                               i64 F3, i64 faceElems) {
    i64 i = (i64)blockIdx.x * 256 + threadIdx.x;
    if (i >= F3) return;
    i64 o = (i64)blockIdx.y * F3 + i;
    if (o < faceElems) __builtin_nontemporal_store((float)faces[i], out1 + o);
}

// vectorized faces with batch loop inside: read once, write B times.
__global__ __launch_bounds__(256) void k_faces4b(const int4* __restrict__ faces4,
                                                 float* __restrict__ out1,
                                                 i64 Fq, i64 F3, int B) {
    i64 t = (i64)blockIdx.x * 256 + threadIdx.x;
    if (t >= Fq) return;
    int4 u = faces4[t];
    float a = (float)u.x, b = (float)u.y, c = (float)u.z, d = (float)u.w;
    for (int bb = 0; bb < B; ++bb) {
        float* p = out1 + (i64)bb * F3 + t * 4;
        __builtin_nontemporal_store(a, p);
        __builtin_nontemporal_store(b, p + 1);
        __builtin_nontemporal_store(c, p + 2);
        __builtin_nontemporal_store(d, p + 3);
    }
}

// ================= generic H path (correctness fallback, H <= 64) =================
__global__ __launch_bounds__(256) void k_l1_g(const float* __restrict__ x,
                                              const float* __restrict__ W1,
                                              const float* __restrict__ dinv,
                                              bf16* __restrict__ P, float* __restrict__ Q,
                                              int b0, int V, int H) {
    extern __shared__ float sW[];
    for (int i = threadIdx.x; i < 3 * H; i += 256) sW[i] = W1[i];
    __syncthreads();
    int v = blockIdx.x * 256 + threadIdx.x;
    if (v >= V) return;
    i64 n = (i64)(b0 + blockIdx.y) * V + v;
    i64 m = (i64)blockIdx.y * V + v;
    float di = dinv[v];
    float x0 = x[n * 3], x1 = x[n * 3 + 1], x2 = x[n * 3 + 2];
    for (int f = 0; f < H; ++f) {
        float g = di * (x0 * sW[f] + x1 * sW[H + f] + x2 * sW[2 * H + f]);
        P[m * H + f] = __float2bfloat16(g);
        Q[m * H + f] = g;
    }
}

__global__ __launch_bounds__(256) void k_scatter_g(const int* __restrict__ edges,
                                                   const bf16* __restrict__ P,
                                                   float* __restrict__ Q,
                                                   int E, int V, int H) {
    int e = blockIdx.x * 256 + threadIdx.x;
    if (e >= E) return;
    int b = blockIdx.y;
    int s = edges[2 * e], d = edges[2 * e + 1];
    for (int f = 0; f < H; ++f)
        unsafeAtomicAdd(&Q[((i64)b * V + d) * H + f], b2f(P[((i64)b * V + s) * H + f]));
}

__global__ __launch_bounds__(256) void k_l2_g(const float* __restrict__ W2,
                                              const float* __restrict__ b1,
                                              const float* __restrict__ dinv,
                                              bf16* __restrict__ P, float* __restrict__ Q,
                                              int V, int H) {
    extern __shared__ float sW[];  // H*H + H
    float* sb = sW + H * H;
    for (int i = threadIdx.x; i < H * H; i += 256) sW[i] = W2[i];
    for (int i = threadIdx.x; i < H; i += 256) sb[i] = b1[i];
    __syncthreads();
    int v = blockIdx.x * 256 + threadIdx.x;
    if (v >= V) return;
    i64 m = (i64)blockIdx.y * V + v;
    float di = dinv[v];
    float h[64];
    for (int k = 0; k < H; ++k) h[k] = lrelu(di * Q[m * H + k] + sb[k]);
    for (int f = 0; f < H; ++f) {
        float a = 0.f;
        for (int k = 0; k < H; ++k) a += h[k] * sW[k * H + f];
        float g = di * a;
        P[m * H + f] = __float2bfloat16(g);
        Q[m * H + f] = g;
    }
}

__global__ __launch_bounds__(256) void k_l3_g(const float* __restrict__ W3,
                                              const float* __restrict__ b2,
                                              const float* __restrict__ dinv,
                                              float* __restrict__ R,
                                              const float* __restrict__ Q, int V, int H) {
    extern __shared__ float sW[];  // H*3 + H
    float* sb = sW + H * 3;
    for (int i = threadIdx.x; i < H * 3; i += 256) sW[i] = W3[i];
    for (int i = threadIdx.x; i < H; i += 256) sb[i] = b2[i];
    __syncthreads();
    int v = blockIdx.x * 256 + threadIdx.x;
    if (v >= V) return;
    i64 m = (i64)blockIdx.y * V + v;
    float di = dinv[v];
    float g0 = 0.f, g1 = 0.f, g2 = 0.f;
    for (int k = 0; k < H; ++k) {
        float h = lrelu(di * Q[m * H + k] + sb[k]);
        g0 += h * sW[k * 3]; g1 += h * sW[k * 3 + 1]; g2 += h * sW[k * 3 + 2];
    }
    ((float4*)R)[m] = make_float4(di * g0, di * g1, di * g2, 0.f);
}

extern "C" void kernel_launch(void* const* d_in, const int* in_sizes, int n_in,
                              void* d_out, int out_size, void* d_ws, size_t ws_size,
                              hipStream_t stream) {
    const float* verts = (const float*)d_in[0];
    const int*   edges = (const int*)d_in[1];
    const int*   faces = (const int*)d_in[2];
    const float* W1 = (const float*)d_in[3];
    const float* b1 = (const float*)d_in[4];
    const float* W2 = (const float*)d_in[5];
    const float* b2 = (const float*)d_in[6];
    const float* W3 = (const float*)d_in[7];
    const float* b3 = (const float*)d_in[8];

    // ---- derive actual dims from in_sizes / out_size ----
    const i64 s0 = in_sizes[0];            // 3*B*V
    const i64 E  = in_sizes[1] / 2;
    const i64 F  = in_sizes[2] / 3;
    const int H  = in_sizes[4];            // b1 length
    i64 B = 0;
    const i64 denomB = 3 * (E + F);        // faces broadcast per batch
    if ((i64)out_size > s0 && denomB > 0) {
        i64 Bc = ((i64)out_size - s0) / denomB;
        if (Bc >= 1 && s0 + Bc * denomB == (i64)out_size && s0 % (3 * Bc) == 0) B = Bc;
    }
    if (B == 0) {                          // fallback: faces stored once (not broadcast)
        i64 num = (i64)out_size - s0 - 3 * F;
        if (num > 0 && E > 0 && num % (3 * E) == 0) {
            i64 Bc = num / (3 * E);
            if (Bc >= 1 && s0 % (3 * Bc) == 0) B = Bc;
        }
    }
    if (B == 0) B = 16;                    // last resort
    const i64 V = s0 / (3 * B);

    // ---- workspace layout ----
    const i64 Vp  = (V + 255) & ~255LL;
    const i64 NB1 = Vp >> 8;               // scan block capacity
    const size_t AUX = (size_t)Vp * 4 * 6  /* dinv_o,dinv_p,indeg,slotOf,sperm,deg_p */
                     + (size_t)(Vp + 256) * 4 /*rowptr*/
                     + (size_t)(NB1 + 256) * 4 /*bsum*/
                     + 192 * 4 /*hist trio*/
                     + (size_t)Vp * 8 /*rp2*/
                     + (size_t)E * 16 /*ep + col_o + col_p*/ + 4096;
    const size_t rowB = (size_t)(6 * H) + 96 + 64;   // buffers/row + slack
    i64 CB = B;
    while (CB > 1 && AUX + (size_t)CB * V * rowB + 8192 > ws_size) CB = (CB + 1) / 2;

    float* ws     = (float*)d_ws;
    float* dinv_o = ws;
    float* dinv_p = ws + Vp;
    int*   indeg  = (int*)(ws + 2 * Vp);
    int*   slotOf = indeg + Vp;
    int*   sperm  = slotOf + Vp;
    int*   deg_p  = sperm + Vp;
    int*   rowptr = deg_p + Vp;            // Vp+256
    int*   bsum   = rowptr + Vp + 256;     // NB1+256
    int*   hist   = bsum + NB1 + 256;      // 64
    int*   hbase  = hist + 64;
    int*   hcnt   = hbase + 64;
    int2*  rp2    = (int2*)(((size_t)(hcnt + 64) + 15) & ~(size_t)15);
    int2*  ep     = rp2 + Vp;
    int*   col_o  = (int*)(ep + E);
    int*   col_p  = col_o + E;
    char*  base   = (char*)(((size_t)(col_p + E) + 255) & ~(size_t)255);
    auto pad = [](size_t x) { return (x + 255) & ~(size_t)255; };

    bf16 *PB = nullptr, *Pg = nullptr;
    float *Q, *R, *Vb;
    {
        char* p = base;
        if (H == 16) {
            PB = (bf16*)p;  p += pad((size_t)CB * V * 32);
            Q  = (float*)p; p += pad((size_t)CB * V * 64);
        } else {
            Pg = (bf16*)p;  p += pad((size_t)CB * V * 2 * H);
            Q  = (float*)p; p += pad((size_t)CB * V * 4 * H);
        }
        R  = (float*)p; p += pad((size_t)CB * V * 16);
        Vb = (float*)p;
    }

    const unsigned NBv = (unsigned)((V + 255) / 256);
    const unsigned NBe = (unsigned)((E + 255) / 256);

    // ---- degrees + degree-sorted permutation + permuted CSR (built once) ----
    hipMemsetAsync(indeg, 0, V * sizeof(int), stream);
    if (NBe) k_deg<<<dim3(NBe), 256, 0, stream>>>(edges, indeg, (int)E);
    if (H == 16) {
        hipMemsetAsync(hist, 0, 64 * sizeof(int), stream);
        k_hist<<<dim3(NBv), 256, 0, stream>>>(indeg, hist, (int)V);
        k_hscan<<<dim3(1), 64, 0, stream>>>(hist, hbase, hcnt);
        k_place<<<dim3(NBv), 256, 0, stream>>>(indeg, hbase, hcnt, slotOf, sperm,
                                               deg_p, dinv_o, dinv_p, (int)V);
    } else {
        k_ident<<<dim3(NBv), 256, 0, stream>>>(indeg, slotOf, sperm, deg_p,
                                               dinv_o, dinv_p, (int)V);
    }
    k_scan1<<<dim3(NBv), 256, 0, stream>>>(deg_p, rowptr, bsum, (int)V);
    k_scan2<<<dim3(1), 1024, 0, stream>>>(bsum, (int)NBv);
    k_scan3<<<dim3(NBv), 256, 0, stream>>>(rowptr, bsum, (int)V, (int)E);
    k_rp2<<<dim3(NBv), 256, 0, stream>>>(rowptr, rp2, (int)V);
    hipMemsetAsync(indeg, 0, V * sizeof(int), stream);  // reuse as fill cursor
    if (NBe) k_fill2<<<dim3(NBe), 256, 0, stream>>>(edges, rowptr, slotOf, indeg,
                                                    col_o, col_p, ep, (int)E);

    float* out0 = (float*)d_out;
    const i64 vertElems = B * (V + E) * 3;
    float* out1 = out0 + vertElems;
    const i64 faceElems = (i64)out_size - vertElems;

    for (i64 b0 = 0; b0 < B; b0 += CB) {
        const i64 CBc = (B - b0 < CB) ? (B - b0) : CB;
        dim3 g1((unsigned)(NBv * CBc));
        dim3 g1e((unsigned)(NBe * CBc));
        if (H == 16) {
            k_gl12<<<g1, 256, 0, stream>>>(rp2, col_o, sperm, verts, W1, b1, W2,
                                           dinv_o, dinv_p, PB, Q,
                                           (int)b0, (int)V, (int)NBv, (int)CBc);
            k_gl3<<<g1, 256, 0, stream>>>(rp2, col_p, W3, b2, dinv_p, PB, Q, R,
                                          (int)V, (int)NBv, (int)CBc);
        } else {
            dim3 gn(NBv, (unsigned)CBc);
            dim3 ge(NBe, (unsigned)CBc);
            size_t sh1 = (size_t)3 * H * 4;
            size_t sh2 = ((size_t)H * H + H) * 4;
            size_t sh3 = ((size_t)H * 3 + H) * 4;
            k_l1_g<<<gn, 256, sh1, stream>>>(verts, W1, dinv_o, Pg, Q, (int)b0, (int)V, H);
            if (NBe) k_scatter_g<<<ge, 256, 0, stream>>>(edges, Pg, Q, (int)E, (int)V, H);
            k_l2_g<<<gn, 256, sh2, stream>>>(W2, b1, dinv_o, Pg, Q, (int)V, H);
            if (NBe) k_scatter_g<<<ge, 256, 0, stream>>>(edges, Pg, Q, (int)E, (int)V, H);
            k_l3_g<<<gn, 256, sh3, stream>>>(W3, b2, dinv_o, R, Q, (int)V, H);
        }
        k_gvert<<<g1, 256, 0, stream>>>(rp2, col_p, sperm, verts, b3, dinv_p, R, Vb,
                                        out0, (int)b0, (int)V, (int)E, (int)NBv, (int)CBc);
        if (NBe) k_mid<<<g1e, 256, 0, stream>>>(ep, Vb, out0, (int)b0, (int)V, (int)E,
                                                (int)NBe, (int)CBc);
    }
    const i64 F3 = 3 * F;
    if (faceElems > 0 && F3 > 0) {
        bool v4 = ((F3 & 3) == 0) && ((vertElems & 3) == 0) && (faceElems == B * F3);
        if (v4) {
            const i64 Fq = F3 >> 2;
            k_faces4b<<<dim3((unsigned)((Fq + 255) / 256)), 256, 0, stream>>>(
                (const int4*)faces, out1, Fq, F3, (int)B);
        } else {
            k_faces<<<dim3((unsigned)((F3 + 255) / 256), (unsigned)B), 256, 0, stream>>>(
                faces, out1, F3, faceElems);
        }
    }
}